// Round 1
// 1752.054 us; speedup vs baseline: 1.0170x; 1.0170x over previous
//
#include <hip/hip_runtime.h>

typedef _Float16 h8 __attribute__((ext_vector_type(8)));
typedef _Float16 h4 __attribute__((ext_vector_type(4)));
typedef float f4 __attribute__((ext_vector_type(4)));

#define SEQ_LEN 50
#define HID 64
#define HS 72  // halves per h row: 144B pitch; 16B-aligned b128 reads

#if __has_builtin(__builtin_amdgcn_exp2f)
#define EXP2(x) __builtin_amdgcn_exp2f(x)
#else
extern "C" __device__ float __ocml_native_exp2_f32(float);
#define EXP2(x) __ocml_native_exp2_f32(x)
#endif
#define RCP(x) __builtin_amdgcn_rcpf(x)

#if __has_builtin(__builtin_amdgcn_mfma_f32_16x16x16f16)
#define HAVE_MFMA16 1
#else
#define HAVE_MFMA16 0
#endif

#define LOG2E  1.442695041f
#define LOG2E2 2.885390082f

// TRANSPOSED orientation: gates^T = W_ext @ [h; x; 1].
// Block = 128 threads = 2 waves, 16 sequences. Wave w owns units 32w..32w+31.
// A (static, registers) = W rows; B (per step) = h from LDS, 2x ds_read_b128.
// D layout: col=lane&15 = seq, row=quad*4+r = unit -> lane's 4 outputs are
// consecutive units of one seq -> single ds_write_b64 per d-group.
// x-projection folded into an MFMA with C=0 (A_x nonzero only in quad 0);
// R7: uses 16x16x16f16 (h4 operands) since only k=0,1 are live -> -16 VGPR.
//
// Activation math (R6+R7): gate pre-acts arrive pre-scaled (i,f,o by log2e;
// g by 2log2e; folded into A). Cell kept in the 2log2e-scaled domain.
//   Ei=2^-ai', Ef=2^-af', Eg=2^g', Eo=2^-ao':
//   c' = [c*pi*pg + L2*(Eg-1)*pf] / (pf*pi*pg)
//   h  = (Ec-1) / (po*(Ec+1)),  Ec = 2^c'
// R7: trans @16cyc/wave64 is ~79% of issue -> share one rcp across a PAIR of
// units at both sites: R=rcp(Da*Db); 1/Da=R*Db; 1/Db=R*Da.  7->6 trans/unit.
// Overflow safety of paired products requires c' clamp <= 40 (tanh(40/2L2)
// = 1-2e-12 == fp32 1.0, so no output change; pre-acts are data-bounded
// <= ~14 scaled so Da*Db <= ~2^105 < inf).
__global__ __launch_bounds__(128, 3)
void lstm_fused(const float* __restrict__ x,
                const float* __restrict__ W_ih,
                const float* __restrict__ W_hh,
                const float* __restrict__ b_ih,
                const float* __restrict__ b_hh,
                const float* __restrict__ W_fc,
                const float* __restrict__ b_fc,
                float* __restrict__ out)
{
    __shared__ _Float16 sH[2][16 * HS];    // h double-buffer: h[seq][unit], fp16
    __shared__ float    sXT[SEQ_LEN * 16]; // x tile, transposed [t][seq]

    const int tid  = threadIdx.x;
    const int wave = tid >> 6;
    const int lane = tid & 63;
    const int col  = lane & 15;
    const int quad = lane >> 4;
    const int seqBase = blockIdx.x << 4;

    // ---- stage x transposed: sXT[t*16 + s] = x[(seqBase+s)*50 + t]
    for (int i = tid; i < SEQ_LEN * 16; i += 128) {
        const int s = i & 15;
        const int t = i >> 4;
        sXT[t * 16 + s] = x[(size_t)(seqBase + s) * SEQ_LEN + t];
    }
    // ---- zero both h buffers (h0 = 0)
    for (int i = tid; i < 2 * 16 * HS; i += 128)
        ((_Float16*)sH)[i] = (_Float16)0.0f;

    // ---- W_hh rows as resident fp16 A-fragments, pre-scaled (i,f,o: log2e;
    // g: 2log2e). A[m=col][k=quad*8+j] = W[unit][kf*32+quad*8+j].
    // A_x: {w_ih*scale, b*scale} at k=0,1 — nonzero only for quad 0.
    h8 Aw[8][2];
#if HAVE_MFMA16
    h4 Ax[8];   // 16x16x16: A[m=col][k=quad*4+j]; only quad0 j=0,1 nonzero
#else
    h8 Ax[8];
#endif
    #pragma unroll
    for (int gi = 0; gi < 4; ++gi) {
        const float scale = (gi == 2) ? LOG2E2 : LOG2E;
        #pragma unroll
        for (int d = 0; d < 2; ++d) {
            const int tt = gi * 2 + d;
            const int n  = (gi * 4 + 2 * wave + d) * 16 + col;
#if HAVE_MFMA16
            h4 axf = {};
#else
            h8 axf = {};
#endif
            if (quad == 0) {
                axf[0] = (_Float16)(W_ih[n] * scale);
                axf[1] = (_Float16)((b_ih[n] + b_hh[n]) * scale);
            }
            Ax[tt] = axf;
            #pragma unroll
            for (int kf = 0; kf < 2; ++kf) {
                const float* wp = W_hh + n * HID + kf * 32 + quad * 8;
                f4 lo = *(const f4*)wp;
                f4 hi = *(const f4*)(wp + 4);
                h8 b;
                b[0] = (_Float16)(lo[0] * scale); b[1] = (_Float16)(lo[1] * scale);
                b[2] = (_Float16)(lo[2] * scale); b[3] = (_Float16)(lo[3] * scale);
                b[4] = (_Float16)(hi[0] * scale); b[5] = (_Float16)(hi[1] * scale);
                b[6] = (_Float16)(hi[2] * scale); b[7] = (_Float16)(hi[3] * scale);
                Aw[tt][kf] = b;
            }
        }
    }

    const f4 z4 = {0.0f, 0.0f, 0.0f, 0.0f};

    // cell state, kept in the 2log2e-scaled domain
    float c[2][4];
    #pragma unroll
    for (int d = 0; d < 2; ++d)
        #pragma unroll
        for (int r = 0; r < 4; ++r) c[d][r] = 0.0f;

    __syncthreads();

    #pragma unroll 2
    for (int t = 0; t < SEQ_LEN; ++t) {
        const _Float16* hb = sH[t & 1];
        _Float16*       hw = sH[(t + 1) & 1];

        // B_x = {x_t[seq], 1, ...}: only k=0,1 (quad0 lanes of A_x) matter.
        const float xt = sXT[t * 16 + col];
#if HAVE_MFMA16
        h4 bx = {};
#else
        h8 bx = {};
#endif
        bx[0] = (_Float16)xt;
        bx[1] = (_Float16)1.0f;

        // B = h^T fragments: B[k=quad*8+j][n=col] = h[col][kf*32+quad*8+j]
        const h8 Bh0 = *(const h8*)(hb + col * HS + quad * 8);
        const h8 Bh1 = *(const h8*)(hb + col * HS + 32 + quad * 8);

        // Two d-groups: 4 live accumulators each (i,f,g,o of the same units)
        #pragma unroll
        for (int d = 0; d < 2; ++d) {
            f4 acc[4];
            #pragma unroll
            for (int gi = 0; gi < 4; ++gi) {
                const int tt = gi * 2 + d;
#if HAVE_MFMA16
                f4 a = __builtin_amdgcn_mfma_f32_16x16x16f16(Ax[tt], bx, z4, 0, 0, 0);
#else
                f4 a = __builtin_amdgcn_mfma_f32_16x16x32_f16(Ax[tt], bx, z4, 0, 0, 0);
#endif
                a = __builtin_amdgcn_mfma_f32_16x16x32_f16(Aw[tt][0], Bh0, a, 0, 0, 0);
                a = __builtin_amdgcn_mfma_f32_16x16x32_f16(Aw[tt][1], Bh1, a, 0, 0, 0);
                acc[gi] = a;
            }
            // paired-rcp activations: 5 exp2 + 1 rcp = 6 trans/unit
            h4 hv;
            #pragma unroll
            for (int rp = 0; rp < 2; ++rp) {
                const int r0 = rp * 2, r1 = r0 + 1;
                float EiA = EXP2(-acc[0][r0]);
                float EfA = EXP2(-acc[1][r0]);
                float EgA = EXP2( acc[2][r0]);
                float EoA = EXP2(-acc[3][r0]);
                float EiB = EXP2(-acc[0][r1]);
                float EfB = EXP2(-acc[1][r1]);
                float EgB = EXP2( acc[2][r1]);
                float EoB = EXP2(-acc[3][r1]);
                float piA = 1.0f + EiA, pfA = 1.0f + EfA;
                float pgA = 1.0f + EgA, poA = 1.0f + EoA;
                float piB = 1.0f + EiB, pfB = 1.0f + EfB;
                float pgB = 1.0f + EgB, poB = 1.0f + EoB;
                float t1A = piA * pgA,  t1B = piB * pgB;
                float DA  = pfA * t1A,  DB  = pfB * t1B;
                float vA  = fmaf(EgA, pfA, -pfA) * LOG2E2;   // L2*(Eg-1)*pf
                float vB  = fmaf(EgB, pfB, -pfB) * LOG2E2;
                float numA = fmaf(c[d][r0], t1A, vA);
                float numB = fmaf(c[d][r1], t1B, vB);
                float R   = RCP(DA * DB);                    // shared rcp #1
                float cnA = fminf(numA * (R * DB), 40.0f);   // overflow guard
                float cnB = fminf(numB * (R * DA), 40.0f);
                c[d][r0] = cnA;
                c[d][r1] = cnB;
                float EcA = EXP2(cnA), EcB = EXP2(cnB);
                float DhA = fmaf(poA, EcA, poA);             // po*(1+Ec)
                float DhB = fmaf(poB, EcB, poB);
                float R2  = RCP(DhA * DhB);                  // shared rcp #2
                float rhA = R2 * DhB,  rhB = R2 * DhA;
                hv[r0] = (_Float16)fmaf(EcA, rhA, -rhA);     // (Ec-1)*rh
                hv[r1] = (_Float16)fmaf(EcB, rhB, -rhB);
            }
            *(h4*)(hw + col * HS + 32 * wave + 16 * d + quad * 4) = hv;
        }
        __syncthreads();
    }

    // ---- epilogue: final h in sH[0], layout h[seq][unit] stride HS
    if (lane < 24) {
        const int sl = wave * 8 + lane / 3;  // sequence within tile
        const int nc = lane % 3;             // class
        const _Float16* hp = sH[0] + sl * HS;
        float a = b_fc[nc];
        #pragma unroll
        for (int u = 0; u < HID; ++u)
            a = fmaf((float)hp[u], W_fc[nc * HID + u], a);
        out[(size_t)(seqBase + sl) * 3 + nc] = a;
    }
}

extern "C" void kernel_launch(void* const* d_in, const int* in_sizes, int n_in,
                              void* d_out, int out_size, void* d_ws, size_t ws_size,
                              hipStream_t stream) {
    const float* x    = (const float*)d_in[0];
    const float* W_ih = (const float*)d_in[1];
    const float* W_hh = (const float*)d_in[2];
    const float* b_ih = (const float*)d_in[3];
    const float* b_hh = (const float*)d_in[4];
    const float* W_fc = (const float*)d_in[5];
    const float* b_fc = (const float*)d_in[6];
    float* out = (float*)d_out;

    const int nSeq   = in_sizes[0] / SEQ_LEN;  // 512000
    const int blocks = nSeq / 16;              // 32000

    hipLaunchKernelGGL(lstm_fused, dim3(blocks), dim3(128), 0, stream,
                       x, W_ih, W_hh, b_ih, b_hh, W_fc, b_fc, out);
}